// Round 1
// baseline (816.880 us; speedup 1.0000x reference)
//
#include <hip/hip_runtime.h>

#define B_TOTAL 4096
#define NVARS   128
#define NMOD    128
#define HID     256

typedef __attribute__((ext_vector_type(8))) __bf16 bf16x8;
typedef __attribute__((ext_vector_type(4))) float  f32x4;

__device__ __forceinline__ unsigned short f2bf(float f) {
    unsigned int u = __builtin_bit_cast(unsigned int, f);
    u += 0x7FFFu + ((u >> 16) & 1u);   // round-to-nearest-even
    return (unsigned short)(u >> 16);
}

// ---------------------------------------------------------------------------
// fp32 -> bf16 weight conversion (done once per launch; weights then L2/L3-hot)
// ---------------------------------------------------------------------------
__global__ __launch_bounds__(256) void k_cvt(const float* __restrict__ in,
                                             ushort4* __restrict__ out, int n4) {
    int i = blockIdx.x * 256 + threadIdx.x;
    if (i < n4) {
        float4 v = ((const float4*)in)[i];
        ushort4 o;
        o.x = f2bf(v.x); o.y = f2bf(v.y); o.z = f2bf(v.z); o.w = f2bf(v.w);
        out[i] = o;
    }
}

// ---------------------------------------------------------------------------
// Xm[t][b][j] = bf16( mask_n2m[b][j][t] * x[b][j] )  — per-b 128x128 transpose
// ---------------------------------------------------------------------------
__global__ __launch_bounds__(256) void k_maskx(const float* __restrict__ mask,
                                               const float* __restrict__ x,
                                               unsigned short* __restrict__ Xm) {
    const int b = blockIdx.x;
    const int tid = threadIdx.x;
    __shared__ float xs[NVARS];
    __shared__ __align__(16) unsigned short ldsT[NVARS * 136];  // [t][j], pad->16B rows

    if (tid < NVARS) xs[tid] = x[(size_t)b * NVARS + tid];
    __syncthreads();

    const float* mrow = mask + (size_t)b * (NVARS * NMOD);
    // phase 1: read [j][t] coalesced (t fastest), scale by x[j], scatter to [t][j]
    #pragma unroll
    for (int it = 0; it < 16; ++it) {
        int idx4 = it * 256 + tid;        // float4 index
        int flat = idx4 * 4;
        int j  = flat >> 7;               // variable index
        int t0 = flat & 127;              // module index (4 consecutive)
        float4 mv = *(const float4*)(mrow + flat);
        float xv = xs[j];
        ldsT[(t0 + 0) * 136 + j] = f2bf(mv.x * xv);
        ldsT[(t0 + 1) * 136 + j] = f2bf(mv.y * xv);
        ldsT[(t0 + 2) * 136 + j] = f2bf(mv.z * xv);
        ldsT[(t0 + 3) * 136 + j] = f2bf(mv.w * xv);
    }
    __syncthreads();
    // phase 2: write [t][j] rows coalesced (256B per row)
    #pragma unroll
    for (int it = 0; it < 8; ++it) {
        int idx = it * 256 + tid;
        int t = idx >> 4;
        int c = idx & 15;
        uint4 v = *(const uint4*)(ldsT + t * 136 + c * 8);
        *(uint4*)(Xm + ((size_t)t * B_TOTAL + b) * NVARS + c * 8) = v;
    }
}

// ---------------------------------------------------------------------------
// Fused 3-layer per-module MLP.  block = (module t, 64-row batch tile)
//   H0 = lrelu(Xm @ W0^T + b0)   [64,256], K=128   (MFMA)
//   H1 = lrelu(H0 @ W1^T + b1)   [64,256], K=256   (MFMA)
//   h  = H1 . W2 + b2            (in-register dot + shuffle reduce)
// MFMA 16x16x32 bf16 layouts (m89/m91-verified):
//   A/B: lane l -> row (l&15), k = (l>>4)*8 + j (8 contiguous)
//   C/D: lane l, reg r -> row (l>>4)*4 + r, col (l&15)
// ---------------------------------------------------------------------------
__global__ __launch_bounds__(256, 2) void k_mlp(
    const unsigned short* __restrict__ Xm,   // [128][4096][128] bf16
    const unsigned short* __restrict__ W0b,  // [128][256][128] bf16
    const float* __restrict__ b0,            // [128][256]
    const unsigned short* __restrict__ W1b,  // [128][256][256] bf16
    const float* __restrict__ b1,            // [128][256]
    const float* __restrict__ W2,            // [128][256]
    const float* __restrict__ b2,            // [128]
    float* __restrict__ hout)                // [4096][128]
{
    const int t     = blockIdx.y;
    const int brow0 = blockIdx.x * 64;
    const int tid   = threadIdx.x;
    const int w     = tid >> 6;
    const int l     = tid & 63;
    const int quad  = l >> 4;
    const int l16   = l & 15;

    __shared__ __align__(16) unsigned short sA[64 * 136];   // Xm tile bf16
    __shared__ __align__(16) unsigned short sH[64 * 264];   // H0 tile bf16
    __shared__ float hpart[4][64];

    // ---- stage Xm tile: 64 rows x 128 bf16 (16 KB), coalesced 16B chunks ----
    {
        const unsigned short* xsrc = Xm + ((size_t)t * B_TOTAL + brow0) * NVARS;
        #pragma unroll
        for (int it = 0; it < 4; ++it) {
            int idx = it * 256 + tid;
            int r = idx >> 4;
            int c = idx & 15;
            uint4 v = *(const uint4*)(xsrc + (size_t)r * NVARS + c * 8);
            *(uint4*)(sA + r * 136 + c * 8) = v;
        }
    }
    __syncthreads();

    // ---- layer 0 ----
    f32x4 acc[4][4];
    #pragma unroll
    for (int mi = 0; mi < 4; ++mi)
        #pragma unroll
        for (int ni = 0; ni < 4; ++ni)
            acc[mi][ni] = {0.f, 0.f, 0.f, 0.f};

    const unsigned short* w0p = W0b + (size_t)t * HID * NVARS;
    #pragma unroll
    for (int k0 = 0; k0 < NVARS; k0 += 32) {
        bf16x8 a[4];
        #pragma unroll
        for (int mi = 0; mi < 4; ++mi)
            a[mi] = *(const bf16x8*)(sA + (mi * 16 + l16) * 136 + k0 + quad * 8);
        #pragma unroll
        for (int ni = 0; ni < 4; ++ni) {
            int n = w * 64 + ni * 16 + l16;
            bf16x8 bb = *(const bf16x8*)(w0p + n * NVARS + k0 + quad * 8);
            #pragma unroll
            for (int mi = 0; mi < 4; ++mi)
                acc[mi][ni] = __builtin_amdgcn_mfma_f32_16x16x32_bf16(a[mi], bb, acc[mi][ni], 0, 0, 0);
        }
    }

    // ---- epilogue 0: bias + lrelu -> sH (bf16) ----
    {
        float b0v[4];
        #pragma unroll
        for (int ni = 0; ni < 4; ++ni)
            b0v[ni] = b0[t * HID + w * 64 + ni * 16 + l16];
        #pragma unroll
        for (int mi = 0; mi < 4; ++mi) {
            int row = mi * 16 + quad * 4;
            #pragma unroll
            for (int ni = 0; ni < 4; ++ni) {
                int col = w * 64 + ni * 16 + l16;
                #pragma unroll
                for (int r = 0; r < 4; ++r) {
                    float v = acc[mi][ni][r] + b0v[ni];
                    v = v > 0.f ? v : 0.01f * v;
                    sH[(row + r) * 264 + col] = f2bf(v);
                }
            }
        }
    }
    __syncthreads();

    // ---- layer 1 ----
    #pragma unroll
    for (int mi = 0; mi < 4; ++mi)
        #pragma unroll
        for (int ni = 0; ni < 4; ++ni)
            acc[mi][ni] = {0.f, 0.f, 0.f, 0.f};

    const unsigned short* w1p = W1b + (size_t)t * HID * HID;
    #pragma unroll
    for (int k0 = 0; k0 < HID; k0 += 32) {
        bf16x8 a[4];
        #pragma unroll
        for (int mi = 0; mi < 4; ++mi)
            a[mi] = *(const bf16x8*)(sH + (mi * 16 + l16) * 264 + k0 + quad * 8);
        #pragma unroll
        for (int ni = 0; ni < 4; ++ni) {
            int n = w * 64 + ni * 16 + l16;
            bf16x8 bb = *(const bf16x8*)(w1p + n * HID + k0 + quad * 8);
            #pragma unroll
            for (int mi = 0; mi < 4; ++mi)
                acc[mi][ni] = __builtin_amdgcn_mfma_f32_16x16x32_bf16(a[mi], bb, acc[mi][ni], 0, 0, 0);
        }
    }

    // ---- epilogue 1: bias + lrelu, dot with W2 in-register, reduce over l16 ----
    {
        float b1v[4], w2v[4];
        #pragma unroll
        for (int ni = 0; ni < 4; ++ni) {
            int n = t * HID + w * 64 + ni * 16 + l16;
            b1v[ni] = b1[n];
            w2v[ni] = W2[n];
        }
        #pragma unroll
        for (int mi = 0; mi < 4; ++mi) {
            #pragma unroll
            for (int r = 0; r < 4; ++r) {
                float s = 0.f;
                #pragma unroll
                for (int ni = 0; ni < 4; ++ni) {
                    float v = acc[mi][ni][r] + b1v[ni];
                    v = v > 0.f ? v : 0.01f * v;
                    s += v * w2v[ni];
                }
                // reduce across the 16 lanes sharing this quad (cols)
                s += __shfl_xor(s, 1, 64);
                s += __shfl_xor(s, 2, 64);
                s += __shfl_xor(s, 4, 64);
                s += __shfl_xor(s, 8, 64);
                if (l16 == 0) hpart[w][mi * 16 + quad * 4 + r] = s;
            }
        }
    }
    __syncthreads();

    if (tid < 64) {
        float hv = hpart[0][tid] + hpart[1][tid] + hpart[2][tid] + hpart[3][tid] + b2[t];
        hout[(size_t)(brow0 + tid) * NMOD + t] = hv;
    }
}

// ---------------------------------------------------------------------------
// module2node: out[b][v] = sum_m Wm[v][m] * mask_m2n[b][v][m] * h[b][m] + bm[v]
// block = one b; wave handles one v at a time, t contiguous across lanes.
// ---------------------------------------------------------------------------
__global__ __launch_bounds__(256) void k_m2n(const float* __restrict__ m2n,
                                             const float* __restrict__ Wm,
                                             const float* __restrict__ bm,
                                             const float* __restrict__ h,
                                             float* __restrict__ out) {
    const int b = blockIdx.x;
    const int tid = threadIdx.x;
    const int w = tid >> 6;
    const int l = tid & 63;

    __shared__ float hvec[NMOD];
    __shared__ float outv[NVARS];

    if (tid < NMOD) hvec[tid] = h[(size_t)b * NMOD + tid];
    __syncthreads();

    const float hx = hvec[2 * l];
    const float hy = hvec[2 * l + 1];
    const float* mrow = m2n + (size_t)b * (NVARS * NMOD);

    for (int it = 0; it < 32; ++it) {
        int v = it * 4 + w;
        float2 mm = *(const float2*)(mrow + v * NMOD + 2 * l);
        float2 wm = *(const float2*)(Wm + v * NMOD + 2 * l);
        float s = wm.x * mm.x * hx + wm.y * mm.y * hy;
        s += __shfl_xor(s, 1, 64);
        s += __shfl_xor(s, 2, 64);
        s += __shfl_xor(s, 4, 64);
        s += __shfl_xor(s, 8, 64);
        s += __shfl_xor(s, 16, 64);
        s += __shfl_xor(s, 32, 64);
        if (l == 0) outv[v] = s;
    }
    __syncthreads();

    if (tid < NVARS) out[(size_t)b * NVARS + tid] = outv[tid] + bm[tid];
}

// ---------------------------------------------------------------------------
extern "C" void kernel_launch(void* const* d_in, const int* in_sizes, int n_in,
                              void* d_out, int out_size, void* d_ws, size_t ws_size,
                              hipStream_t stream) {
    const float* x    = (const float*)d_in[0];
    const float* mn2m = (const float*)d_in[1];
    const float* mm2n = (const float*)d_in[2];
    const float* W0   = (const float*)d_in[3];
    const float* b0   = (const float*)d_in[4];
    const float* W1   = (const float*)d_in[5];
    const float* b1   = (const float*)d_in[6];
    const float* W2   = (const float*)d_in[7];
    const float* b2   = (const float*)d_in[8];
    const float* Wm   = (const float*)d_in[9];
    const float* bm   = (const float*)d_in[10];
    float* out = (float*)d_out;

    // workspace layout (bytes):
    //   Xm  bf16 [128][4096][128]  = 134,217,728
    //   W0b bf16 [128][256][128]   =   8,388,608
    //   W1b bf16 [128][256][256]   =  16,777,216
    //   h   f32  [4096][128]       =   2,097,152     total ~154 MB
    char* ws = (char*)d_ws;
    unsigned short* Xm  = (unsigned short*)(ws);
    unsigned short* W0b = (unsigned short*)(ws + (size_t)134217728);
    unsigned short* W1b = (unsigned short*)(ws + (size_t)142606336);
    float*          hbuf = (float*)(ws + (size_t)159383552);

    k_cvt  <<<4096, 256, 0, stream>>>(W0, (ushort4*)W0b, 1048576);
    k_cvt  <<<8192, 256, 0, stream>>>(W1, (ushort4*)W1b, 2097152);
    k_maskx<<<4096, 256, 0, stream>>>(mn2m, x, Xm);
    k_mlp  <<<dim3(64, 128), 256, 0, stream>>>(Xm, W0b, b0, W1b, b1, W2, b2, hbuf);
    k_m2n  <<<4096, 256, 0, stream>>>(mm2n, Wm, bm, hbuf, out);
}